// Round 1
// baseline (113.450 us; speedup 1.0000x reference)
//
#include <hip/hip_runtime.h>
#include <math.h>

#define CN 256
#define DN 512

struct Job {
  const float* A; const float* B;
  const float* A2; const float* B2;
  float* Cp;
  const float* bias; const float* rs; const float* base;
};
struct Jobs5 { Job j[5]; };

static inline Job mkjob(const float* A, const float* B, const float* A2, const float* B2,
                        float* Cp, const float* bias, const float* rs, const float* base) {
  Job j; j.A = A; j.B = B; j.A2 = A2; j.B2 = B2; j.Cp = Cp; j.bias = bias; j.rs = rs; j.base = base;
  return j;
}

__device__ __forceinline__ float blockReduceSum256(float v) {
#pragma unroll
  for (int o = 32; o > 0; o >>= 1) v += __shfl_down(v, o, 64);
  __shared__ float red_[4];
  if ((threadIdx.x & 63) == 0) red_[threadIdx.x >> 6] = v;
  __syncthreads();
  return red_[0] + red_[1] + red_[2] + red_[3];
}

// Normalize rows of text/img/neg -> tn/imgn/negn (unit L2 per row, clamp 1e-12)
__global__ __launch_bounds__(256) void norm_k(const float* __restrict__ text,
                                              const float* __restrict__ img,
                                              const float* __restrict__ neg,
                                              float* __restrict__ tn,
                                              float* __restrict__ imgn,
                                              float* __restrict__ negn) {
  const int z = blockIdx.x >> 8, row = blockIdx.x & 255;
  const float* src = z == 0 ? text : (z == 1 ? img : neg);
  float* dst = z == 0 ? tn : (z == 1 ? imgn : negn);
  const int t = threadIdx.x;
  const float x0 = src[row * DN + t];
  const float x1 = src[row * DN + 256 + t];
  const float ss = blockReduceSum256(x0 * x0 + x1 * x1);
  const float inv = 1.f / fmaxf(sqrtf(ss), 1e-12f);
  dst[row * DN + t] = x0 * inv;
  dst[row * DN + 256 + t] = x1 * inv;
}

// Generic tiled GEMM. C[i,j] = epi( sum_k A[i,k]*B(k,j) [+ phase2 A2,B2] )
// BT=1: B is [N,K] (NT form). BT=0: B is [K,N] (NN form).
// EPI: 0 plain store; 1 exp(acc+bias[j]); 2 tanh(rs[i]*acc + bias[i*N+j]);
//      3 acc + 2*rs[i]*base[i*N+j]  (two-phase contraction, A2 may be null)
template <int BT, int EPI>
__global__ __launch_bounds__(256) void gemm_k(Jobs5 js, int N, int K) {
  __shared__ float As[32][33];
  __shared__ float Bs[32][33];
  const Job jb = js.j[blockIdx.z];
  const int bm = blockIdx.y << 5, bn = blockIdx.x << 5;
  const int tid = threadIdx.x;
  const int tx = tid & 15, ty = tid >> 4;
  const int lr = tid >> 3, lc = (tid & 7) << 2;
  float a00 = 0.f, a01 = 0.f, a10 = 0.f, a11 = 0.f;
  const int nph = (EPI == 3) ? 2 : 1;
  for (int ph = 0; ph < nph; ++ph) {
    const float* Ap = ph ? jb.A2 : jb.A;
    const float* Bp = ph ? jb.B2 : jb.B;
    if (!Ap) break;
    for (int k0 = 0; k0 < K; k0 += 32) {
      __syncthreads();
      const float4 av = *(const float4*)(Ap + (size_t)(bm + lr) * K + k0 + lc);
      As[lr][lc + 0] = av.x; As[lr][lc + 1] = av.y; As[lr][lc + 2] = av.z; As[lr][lc + 3] = av.w;
      float4 bv;
      if (BT) bv = *(const float4*)(Bp + (size_t)(bn + lr) * K + k0 + lc);
      else    bv = *(const float4*)(Bp + (size_t)(k0 + lr) * N + bn + lc);
      Bs[lr][lc + 0] = bv.x; Bs[lr][lc + 1] = bv.y; Bs[lr][lc + 2] = bv.z; Bs[lr][lc + 3] = bv.w;
      __syncthreads();
#pragma unroll
      for (int k = 0; k < 32; ++k) {
        const float x0 = As[2 * ty + 0][k], x1 = As[2 * ty + 1][k];
        float y0, y1;
        if (BT) { y0 = Bs[2 * tx + 0][k]; y1 = Bs[2 * tx + 1][k]; }
        else    { y0 = Bs[k][2 * tx + 0]; y1 = Bs[k][2 * tx + 1]; }
        a00 += x0 * y0; a01 += x0 * y1; a10 += x1 * y0; a11 += x1 * y1;
      }
    }
  }
  const int r0 = bm + 2 * ty, c0 = bn + 2 * tx;
  float vals[2][2] = {{a00, a01}, {a10, a11}};
#pragma unroll
  for (int i = 0; i < 2; ++i) {
#pragma unroll
    for (int jx = 0; jx < 2; ++jx) {
      const int r = r0 + i, c = c0 + jx;
      const size_t idx = (size_t)r * N + c;
      const float v = vals[i][jx];
      if (EPI == 0)      jb.Cp[idx] = v;
      else if (EPI == 1) jb.Cp[idx] = expf(v + jb.bias[c]);
      else if (EPI == 2) jb.Cp[idx] = tanhf(jb.rs[r] * v + jb.bias[idx]);
      else               jb.Cp[idx] = v + 2.f * jb.rs[r] * jb.base[idx];
    }
  }
}

// srs[z*256+b] = 1 + sum_j relu(S_z[b,j])
__global__ __launch_bounds__(256) void rowsum_k(const float* __restrict__ S0,
                                                const float* __restrict__ S1,
                                                const float* __restrict__ S2,
                                                float* __restrict__ srs) {
  const float* S = blockIdx.y == 0 ? S0 : (blockIdx.y == 1 ? S1 : S2);
  const int b = blockIdx.x;
  const float v = fmaxf(S[b * CN + threadIdx.x], 0.f);
  const float s = blockReduceSum256(v);
  if (threadIdx.x == 0) srs[blockIdx.y * CN + b] = 1.f + s;
}

// E[z*256+p] = sum_n e_z[n,p]
__global__ __launch_bounds__(256) void colsum_k(const float* __restrict__ e0,
                                                const float* __restrict__ e1,
                                                float* __restrict__ E) {
  const float* e = blockIdx.y ? e1 : e0;
  const int p = threadIdx.x;
  float s = 0.f;
  for (int n = 0; n < CN; ++n) s += e[n * CN + p];
  E[blockIdx.y * CN + p] = s;
}

// c[z][b,m] = relu(R)*rsqrt(srs[m]+relu(R));  d0[z][b] = rsqrt(2 + sum_m relu(R))
__global__ __launch_bounds__(256) void cd0_k(const float* __restrict__ R0,
                                             const float* __restrict__ R1,
                                             const float* __restrict__ R2,
                                             const float* __restrict__ srs,
                                             float* __restrict__ cmat,
                                             float* __restrict__ d0) {
  const int z = blockIdx.y;
  const float* R = z == 0 ? R0 : (z == 1 ? R1 : R2);
  const int b = blockIdx.x, m = threadIdx.x;
  const float r = fmaxf(R[b * CN + m], 0.f);
  cmat[(size_t)z * CN * CN + b * CN + m] = r * rsqrtf(srs[z * CN + m] + r);
  const float s = blockReduceSum256(r);
  if (m == 0) d0[z * CN + b] = rsqrtf(2.f + s);
}

// h = (2*d0[b]*e0 + g) / (e0 + E[p])
__global__ __launch_bounds__(256) void h_k(const float* __restrict__ eT, const float* __restrict__ g_t,
                                           const float* __restrict__ Et, const float* __restrict__ d0t,
                                           float* __restrict__ h_t,
                                           const float* __restrict__ e0I, const float* __restrict__ g_i,
                                           const float* __restrict__ Ei, const float* __restrict__ d0i,
                                           float* __restrict__ h_i) {
  const int b = blockIdx.x, p = threadIdx.x, idx = b * CN + p;
  if (blockIdx.y == 0) {
    const float e = eT[idx];
    h_t[idx] = (2.f * d0t[b] * e + g_t[idx]) / (e + Et[p]);
  } else {
    const float e = e0I[idx];
    h_i[idx] = (2.f * d0i[b] * e + g_i[idx]) / (e + Ei[p]);
  }
}

// main = 0.5*text + 0.35*o_tt + 0.15*o_it ; tail copy img_feature
__global__ __launch_bounds__(256) void combine_k(const float* __restrict__ text,
                                                 const float* __restrict__ ott,
                                                 const float* __restrict__ oit,
                                                 const float* __restrict__ imgf,
                                                 float* __restrict__ out) {
  const int i = blockIdx.x * 256 + threadIdx.x;
  if (i < CN * DN) out[i] = 0.5f * text[i] + 0.35f * ott[i] + 0.15f * oit[i];
  else             out[4 * CN * DN + (i - CN * DN)] = imgf[i - CN * DN];
}

extern "C" void kernel_launch(void* const* d_in, const int* in_sizes, int n_in,
                              void* d_out, int out_size, void* d_ws, size_t ws_size,
                              hipStream_t stream) {
  const float* img_feature = (const float*)d_in[0];
  const float* text = (const float*)d_in[1];
  const float* img  = (const float*)d_in[2];
  const float* neg  = (const float*)d_in[3];
  const float* p_list_t = (const float*)d_in[4];
  const float* a_w_t = (const float*)d_in[5];
  const float* a_b_t = (const float*)d_in[6];
  const float* p_list_i = (const float*)d_in[7];
  const float* a_w_i = (const float*)d_in[8];
  const float* a_b_i = (const float*)d_in[9];
  const float* W_tt  = (const float*)d_in[10];
  const float* b_tt  = (const float*)d_in[11];
  const float* W_it  = (const float*)d_in[12];
  const float* b_it  = (const float*)d_in[13];
  const float* W_ntt = (const float*)d_in[14];
  const float* b_ntt = (const float*)d_in[15];
  float* out = (float*)d_out;
  float* w = (float*)d_ws;

  float* tn    = w + 0;
  float* imgn  = w + 131072;
  float* negn  = w + 262144;
  float* S_tt  = w + 393216;
  float* S_it  = w + 458752;
  float* R_it  = w + 524288;
  float* S_ntt = w + 589824;
  float* R_ntt = w + 655360;
  float* eT    = w + 720896;   // exp(text@a_w_t^T + a_b_t)
  float* eI    = w + 786432;   // exp(img @a_w_i^T + a_b_i)
  float* e0I   = w + 851968;   // exp(text@a_w_i^T + a_b_i)
  float* c0b   = w + 917504;   // c_tt, c_it, c_ntt contiguous (3*65536)
  float* g_t   = w + 1114112;
  float* g_i   = w + 1179648;
  float* h_t   = w + 1245184;
  float* h_i   = w + 1310720;
  float* u_tt  = w + 1376256;
  float* u_it  = w + 1507328;
  float* u_ntt = w + 1638400;
  float* srs   = w + 1769472;  // 3*256 shared row sums
  float* Ecol  = w + 1770240;  // 2*256 (E_t, E_i)
  float* d0    = w + 1770752;  // 3*256

  // 1. normalize
  norm_k<<<768, 256, 0, stream>>>(text, img, neg, tn, imgn, negn);

  // 2. cosine-similarity GEMMs (NT, K=512): S_tt(=R_tt), S_it, R_it, S_ntt, R_ntt
  Jobs5 jS = {};
  jS.j[0] = mkjob(tn,   tn,   0, 0, S_tt,  0, 0, 0);
  jS.j[1] = mkjob(imgn, imgn, 0, 0, S_it,  0, 0, 0);
  jS.j[2] = mkjob(tn,   imgn, 0, 0, R_it,  0, 0, 0);
  jS.j[3] = mkjob(negn, negn, 0, 0, S_ntt, 0, 0, 0);
  jS.j[4] = mkjob(tn,   negn, 0, 0, R_ntt, 0, 0, 0);
  gemm_k<1, 0><<<dim3(8, 8, 5), 256, 0, stream>>>(jS, 256, 512);

  // 3. exp-score GEMMs (NT, K=512, epi=exp(acc+bias))
  Jobs5 jE = {};
  jE.j[0] = mkjob(text, a_w_t, 0, 0, eT,  a_b_t, 0, 0);
  jE.j[1] = mkjob(img,  a_w_i, 0, 0, eI,  a_b_i, 0, 0);
  jE.j[2] = mkjob(text, a_w_i, 0, 0, e0I, a_b_i, 0, 0);
  gemm_k<1, 1><<<dim3(8, 8, 3), 256, 0, stream>>>(jE, 256, 512);

  // 4. shared row sums; 5. softmax-denominator column sums
  rowsum_k<<<dim3(256, 3), 256, 0, stream>>>(S_tt, S_it, S_ntt, srs);
  colsum_k<<<dim3(1, 2), 256, 0, stream>>>(eT, eI, Ecol);

  // 6. adjacency row-0 coefficients c and d0
  cd0_k<<<dim3(256, 3), 256, 0, stream>>>(S_tt, R_it, R_ntt, srs, c0b, d0);

  // 7. g = c @ expScores (NN, K=256)
  Jobs5 jG = {};
  jG.j[0] = mkjob(c0b,         eT, 0, 0, g_t, 0, 0, 0);
  jG.j[1] = mkjob(c0b + 65536, eI, 0, 0, g_i, 0, 0, 0);
  gemm_k<0, 0><<<dim3(8, 8, 2), 256, 0, stream>>>(jG, 256, 256);

  // 8. h = (2*d0*e0 + g) / denom
  h_k<<<dim3(256, 2), 256, 0, stream>>>(eT, g_t, Ecol, d0, h_t,
                                        e0I, g_i, Ecol + 256, d0 + 256, h_i);

  // 9. u = 2*d0*text + h@p_list + c@shared  (NN, K=256, two-phase)
  Jobs5 jU = {};
  jU.j[0] = mkjob(h_t, p_list_t, c0b,          text, u_tt,  0, d0,       text);
  jU.j[1] = mkjob(h_i, p_list_i, c0b + 65536,  img,  u_it,  0, d0 + 256, text);
  jU.j[2] = mkjob(c0b + 131072, neg, 0, 0,           u_ntt, 0, d0 + 512, text);
  gemm_k<0, 3><<<dim3(16, 8, 3), 256, 0, stream>>>(jU, 512, 256);

  // 10. out = tanh(d0*(u@W) + bias)  (NN, K=512) -> straight into d_out slots
  Jobs5 jO = {};
  jO.j[0] = mkjob(u_tt,  W_tt,  0, 0, out + 131072, b_tt,  d0,       0);
  jO.j[1] = mkjob(u_it,  W_it,  0, 0, out + 262144, b_it,  d0 + 256, 0);
  jO.j[2] = mkjob(u_ntt, W_ntt, 0, 0, out + 393216, b_ntt, d0 + 512, 0);
  gemm_k<0, 2><<<dim3(16, 8, 3), 256, 0, stream>>>(jO, 512, 512);

  // 11. main + img_feature passthrough
  combine_k<<<640, 256, 0, stream>>>(text, out + 131072, out + 262144, img_feature, out);
}

// Round 2
// 91.479 us; speedup vs baseline: 1.2402x; 1.2402x over previous
//
#include <hip/hip_runtime.h>
#include <math.h>

#define CN 256
#define DN 512

typedef __attribute__((ext_vector_type(8))) short bf16x8;
typedef __attribute__((ext_vector_type(4))) float f32x4;

__device__ __forceinline__ short f2bf(float f) {
  unsigned u = __float_as_uint(f);
  u += 0x7fffu + ((u >> 16) & 1u);
  return (short)(u >> 16);
}

__device__ __forceinline__ bf16x8 pack8(float4 v0, float4 v1) {
  bf16x8 r;
  r[0] = f2bf(v0.x); r[1] = f2bf(v0.y); r[2] = f2bf(v0.z); r[3] = f2bf(v0.w);
  r[4] = f2bf(v1.x); r[5] = f2bf(v1.y); r[6] = f2bf(v1.z); r[7] = f2bf(v1.w);
  return r;
}

struct JobM {
  const float* A; const float* B; const float* A2; const float* B2;
  float* C; const float* bias; const float* rs; const float* base;
  int epi; int nph;
};
struct Jobs8 { JobM j[8]; };

static inline JobM mkjob(const float* A, const float* B, const float* A2, const float* B2,
                         float* C, const float* bias, const float* rs, const float* base,
                         int epi, int nph) {
  JobM j; j.A = A; j.B = B; j.A2 = A2; j.B2 = B2; j.C = C;
  j.bias = bias; j.rs = rs; j.base = base; j.epi = epi; j.nph = nph;
  return j;
}

// MFMA GEMM: 64x64 block tile, 4 waves (2x2), K-step 32, bf16 inputs converted
// during LDS staging. LDS layout is fragment-major: element (r,k) of a 64x32
// tile lives at short-index ((r>>4)<<9) + ((k>>3)<<7) + ((r&15)<<3) + (k&7),
// so a wave's operand load is ds_read_b128 at group_base + lane*16 (linear,
// conflict-free).
// BT=1: B stored [N][K] (NT). BT=0: B stored [K][N] (NN, scatter-staged).
// epi: 0 store; 1 exp(v+bias[c]); 2 tanh(rs[r]*v+bias[idx]); 3 v+2*rs[r]*base[idx]
template <int BT>
__global__ __launch_bounds__(256) void mgemm_k(Jobs8 js, int N, int K) {
  __shared__ __align__(16) short As[2048];
  __shared__ __align__(16) short Bs[2048];
  const JobM jb = js.j[blockIdx.z];
  const int bm = blockIdx.y << 6, bn = blockIdx.x << 6;
  const int tid = threadIdx.x;
  const int lane = tid & 63, w = tid >> 6;
  const int wr = w >> 1, wc = w & 1;
  f32x4 a00 = {0,0,0,0}, a01 = {0,0,0,0}, a10 = {0,0,0,0}, a11 = {0,0,0,0};

  for (int ph = 0; ph < jb.nph; ++ph) {
    const float* __restrict__ Ap = ph ? jb.A2 : jb.A;
    const float* __restrict__ Bp = ph ? jb.B2 : jb.B;
    for (int k0 = 0; k0 < K; k0 += 32) {
      __syncthreads();
      {  // stage A (always [M][K] row-major): thread t -> row r, k-octet q
        const int r = tid >> 2, q = tid & 3;
        const float4* pa = (const float4*)(Ap + (size_t)(bm + r) * K + (k0 + (q << 3)));
        *(bf16x8*)&As[((r >> 4) << 9) + (q << 7) + ((r & 15) << 3)] = pack8(pa[0], pa[1]);
      }
      if (BT) {  // B [N][K]: identical staging with n = row
        const int n = tid >> 2, q = tid & 3;
        const float4* pb = (const float4*)(Bp + (size_t)(bn + n) * K + (k0 + (q << 3)));
        *(bf16x8*)&Bs[((n >> 4) << 9) + (q << 7) + ((n & 15) << 3)] = pack8(pb[0], pb[1]);
      } else {   // B [K][N]: coalesced row read, scatter 8 b16 writes (transpose)
        const int kr = tid >> 3, c = (tid & 7) << 3;
        const float4* pb = (const float4*)(Bp + (size_t)(k0 + kr) * N + bn + c);
        const float4 v0 = pb[0], v1 = pb[1];
        const float vv[8] = {v0.x, v0.y, v0.z, v0.w, v1.x, v1.y, v1.z, v1.w};
        const int kb = (kr >> 3) << 7, kl = kr & 7;
#pragma unroll
        for (int jx = 0; jx < 8; ++jx) {
          const int n = c + jx;
          Bs[((n >> 4) << 9) + kb + ((n & 15) << 3) + kl] = f2bf(vv[jx]);
        }
      }
      __syncthreads();
      const bf16x8 fa0 = *(const bf16x8*)&As[(((wr << 1) + 0) << 9) + (lane << 3)];
      const bf16x8 fa1 = *(const bf16x8*)&As[(((wr << 1) + 1) << 9) + (lane << 3)];
      const bf16x8 fb0 = *(const bf16x8*)&Bs[(((wc << 1) + 0) << 9) + (lane << 3)];
      const bf16x8 fb1 = *(const bf16x8*)&Bs[(((wc << 1) + 1) << 9) + (lane << 3)];
      a00 = __builtin_amdgcn_mfma_f32_16x16x32_bf16(fa0, fb0, a00, 0, 0, 0);
      a01 = __builtin_amdgcn_mfma_f32_16x16x32_bf16(fa0, fb1, a01, 0, 0, 0);
      a10 = __builtin_amdgcn_mfma_f32_16x16x32_bf16(fa1, fb0, a10, 0, 0, 0);
      a11 = __builtin_amdgcn_mfma_f32_16x16x32_bf16(fa1, fb1, a11, 0, 0, 0);
    }
  }

  const int row0 = bm + wr * 32, col0 = bn + wc * 32;
  const f32x4 accs[2][2] = {{a00, a01}, {a10, a11}};
#pragma unroll
  for (int mi = 0; mi < 2; ++mi)
#pragma unroll
    for (int ni = 0; ni < 2; ++ni) {
      const int c = col0 + ni * 16 + (lane & 15);
      const int rb = row0 + mi * 16 + ((lane >> 4) << 2);
#pragma unroll
      for (int jx = 0; jx < 4; ++jx) {
        const int r = rb + jx;
        const size_t idx = (size_t)r * N + c;
        const float v = accs[mi][ni][jx];
        if (jb.epi == 0)      jb.C[idx] = v;
        else if (jb.epi == 1) jb.C[idx] = expf(v + jb.bias[c]);
        else if (jb.epi == 2) jb.C[idx] = tanhf(jb.rs[r] * v + jb.bias[idx]);
        else                  jb.C[idx] = v + 2.f * jb.rs[r] * jb.base[idx];
      }
    }
}

__device__ __forceinline__ float blockReduceSum256(float v) {
#pragma unroll
  for (int o = 32; o > 0; o >>= 1) v += __shfl_down(v, o, 64);
  __shared__ float red_[4];
  if ((threadIdx.x & 63) == 0) red_[threadIdx.x >> 6] = v;
  __syncthreads();
  return red_[0] + red_[1] + red_[2] + red_[3];
}

__global__ __launch_bounds__(256) void norm_k(const float* __restrict__ text,
                                              const float* __restrict__ img,
                                              const float* __restrict__ neg,
                                              float* __restrict__ tn,
                                              float* __restrict__ imgn,
                                              float* __restrict__ negn) {
  const int z = blockIdx.x >> 8, row = blockIdx.x & 255;
  const float* src = z == 0 ? text : (z == 1 ? img : neg);
  float* dst = z == 0 ? tn : (z == 1 ? imgn : negn);
  const int t = threadIdx.x;
  const float x0 = src[row * DN + t];
  const float x1 = src[row * DN + 256 + t];
  const float ss = blockReduceSum256(x0 * x0 + x1 * x1);
  const float inv = 1.f / fmaxf(sqrtf(ss), 1e-12f);
  dst[row * DN + t] = x0 * inv;
  dst[row * DN + 256 + t] = x1 * inv;
}

// y<3: srs[y*256+b] = 1 + sum_j relu(S_y[b,j])   (grid.x = 256 blocks)
// y>=3: E[(y-3)*256+p] = sum_n e[n,p]            (grid.x: first 8 blocks used)
__global__ __launch_bounds__(256) void sums_k(const float* __restrict__ S0,
                                              const float* __restrict__ S1,
                                              const float* __restrict__ S2,
                                              float* __restrict__ srs,
                                              const float* __restrict__ e0,
                                              const float* __restrict__ e1,
                                              float* __restrict__ E) {
  const int y = blockIdx.y;
  if (y < 3) {
    const float* S = y == 0 ? S0 : (y == 1 ? S1 : S2);
    const int b = blockIdx.x;
    const float v = fmaxf(S[b * CN + threadIdx.x], 0.f);
    const float s = blockReduceSum256(v);
    if (threadIdx.x == 0) srs[y * CN + b] = 1.f + s;
  } else {
    if (blockIdx.x >= 8) return;
    const float* e = (y == 3) ? e0 : e1;
    const int c = blockIdx.x * 32 + (threadIdx.x & 31);
    const int rc = threadIdx.x >> 5;
    float s = 0.f;
#pragma unroll 4
    for (int i = 0; i < 32; ++i) s += e[(rc * 32 + i) * CN + c];
    __shared__ float part[8][32];
    part[rc][threadIdx.x & 31] = s;
    __syncthreads();
    if (rc == 0) {
      float t = 0.f;
#pragma unroll
      for (int i = 0; i < 8; ++i) t += part[i][threadIdx.x & 31];
      E[(y - 3) * CN + c] = t;
    }
  }
}

__global__ __launch_bounds__(256) void cd0_k(const float* __restrict__ R0,
                                             const float* __restrict__ R1,
                                             const float* __restrict__ R2,
                                             const float* __restrict__ srs,
                                             float* __restrict__ cmat,
                                             float* __restrict__ d0) {
  const int z = blockIdx.y;
  const float* R = z == 0 ? R0 : (z == 1 ? R1 : R2);
  const int b = blockIdx.x, m = threadIdx.x;
  const float r = fmaxf(R[b * CN + m], 0.f);
  cmat[(size_t)z * CN * CN + b * CN + m] = r * rsqrtf(srs[z * CN + m] + r);
  const float s = blockReduceSum256(r);
  if (m == 0) d0[z * CN + b] = rsqrtf(2.f + s);
}

__global__ __launch_bounds__(256) void h_k(const float* __restrict__ eT, const float* __restrict__ g_t,
                                           const float* __restrict__ Et, const float* __restrict__ d0t,
                                           float* __restrict__ h_t,
                                           const float* __restrict__ e0I, const float* __restrict__ g_i,
                                           const float* __restrict__ Ei, const float* __restrict__ d0i,
                                           float* __restrict__ h_i) {
  const int b = blockIdx.x, p = threadIdx.x, idx = b * CN + p;
  if (blockIdx.y == 0) {
    const float e = eT[idx];
    h_t[idx] = (2.f * d0t[b] * e + g_t[idx]) / (e + Et[p]);
  } else {
    const float e = e0I[idx];
    h_i[idx] = (2.f * d0i[b] * e + g_i[idx]) / (e + Ei[p]);
  }
}

__global__ __launch_bounds__(256) void combine_k(const float* __restrict__ text,
                                                 const float* __restrict__ ott,
                                                 const float* __restrict__ oit,
                                                 const float* __restrict__ imgf,
                                                 float* __restrict__ out) {
  const int i = blockIdx.x * 256 + threadIdx.x;
  if (i < CN * DN) out[i] = 0.5f * text[i] + 0.35f * ott[i] + 0.15f * oit[i];
  else             out[4 * CN * DN + (i - CN * DN)] = imgf[i - CN * DN];
}

extern "C" void kernel_launch(void* const* d_in, const int* in_sizes, int n_in,
                              void* d_out, int out_size, void* d_ws, size_t ws_size,
                              hipStream_t stream) {
  const float* img_feature = (const float*)d_in[0];
  const float* text = (const float*)d_in[1];
  const float* img  = (const float*)d_in[2];
  const float* neg  = (const float*)d_in[3];
  const float* p_list_t = (const float*)d_in[4];
  const float* a_w_t = (const float*)d_in[5];
  const float* a_b_t = (const float*)d_in[6];
  const float* p_list_i = (const float*)d_in[7];
  const float* a_w_i = (const float*)d_in[8];
  const float* a_b_i = (const float*)d_in[9];
  const float* W_tt  = (const float*)d_in[10];
  const float* b_tt  = (const float*)d_in[11];
  const float* W_it  = (const float*)d_in[12];
  const float* b_it  = (const float*)d_in[13];
  const float* W_ntt = (const float*)d_in[14];
  const float* b_ntt = (const float*)d_in[15];
  float* out = (float*)d_out;
  float* w = (float*)d_ws;

  float* tn    = w + 0;
  float* imgn  = w + 131072;
  float* negn  = w + 262144;
  float* S_tt  = w + 393216;
  float* S_it  = w + 458752;
  float* R_it  = w + 524288;
  float* S_ntt = w + 589824;
  float* R_ntt = w + 655360;
  float* eT    = w + 720896;
  float* eI    = w + 786432;
  float* e0I   = w + 851968;
  float* c0b   = w + 917504;   // c_tt, c_it, c_ntt contiguous (3*65536)
  float* g_t   = w + 1114112;
  float* g_i   = w + 1179648;
  float* h_t   = w + 1245184;
  float* h_i   = w + 1310720;
  float* u_tt  = w + 1376256;
  float* u_it  = w + 1507328;
  float* u_ntt = w + 1638400;
  float* srs   = w + 1769472;  // 3*256
  float* Ecol  = w + 1770240;  // 2*256
  float* d0    = w + 1770752;  // 3*256

  // 1. normalize rows
  norm_k<<<768, 256, 0, stream>>>(text, img, neg, tn, imgn, negn);

  // 2. merged NT GEMMs (K=512, N=256): 5 cosine-sim + 3 exp-score jobs
  Jobs8 jSE = {};
  jSE.j[0] = mkjob(tn,   tn,   0, 0, S_tt,  0, 0, 0, 0, 1);
  jSE.j[1] = mkjob(imgn, imgn, 0, 0, S_it,  0, 0, 0, 0, 1);
  jSE.j[2] = mkjob(tn,   imgn, 0, 0, R_it,  0, 0, 0, 0, 1);
  jSE.j[3] = mkjob(negn, negn, 0, 0, S_ntt, 0, 0, 0, 0, 1);
  jSE.j[4] = mkjob(tn,   negn, 0, 0, R_ntt, 0, 0, 0, 0, 1);
  jSE.j[5] = mkjob(text, a_w_t, 0, 0, eT,  a_b_t, 0, 0, 1, 1);
  jSE.j[6] = mkjob(img,  a_w_i, 0, 0, eI,  a_b_i, 0, 0, 1, 1);
  jSE.j[7] = mkjob(text, a_w_i, 0, 0, e0I, a_b_i, 0, 0, 1, 1);
  mgemm_k<1><<<dim3(4, 4, 8), 256, 0, stream>>>(jSE, 256, 512);

  // 3. shared row sums + softmax-denominator column sums (one launch)
  sums_k<<<dim3(256, 5), 256, 0, stream>>>(S_tt, S_it, S_ntt, srs, eT, eI, Ecol);

  // 4. adjacency row-0 coefficients c and d0
  cd0_k<<<dim3(256, 3), 256, 0, stream>>>(S_tt, R_it, R_ntt, srs, c0b, d0);

  // 5. g = c @ expScores (NN, K=256)
  Jobs8 jG = {};
  jG.j[0] = mkjob(c0b,         eT, 0, 0, g_t, 0, 0, 0, 0, 1);
  jG.j[1] = mkjob(c0b + 65536, eI, 0, 0, g_i, 0, 0, 0, 0, 1);
  mgemm_k<0><<<dim3(4, 4, 2), 256, 0, stream>>>(jG, 256, 256);

  // 6. h = (2*d0*e0 + g) / denom
  h_k<<<dim3(256, 2), 256, 0, stream>>>(eT, g_t, Ecol, d0, h_t,
                                        e0I, g_i, Ecol + 256, d0 + 256, h_i);

  // 7. u = 2*d0*text + h@p_list + c@shared (NN, K=256, two-phase)
  Jobs8 jU = {};
  jU.j[0] = mkjob(h_t, p_list_t, c0b,          text, u_tt,  0, d0,       text, 3, 2);
  jU.j[1] = mkjob(h_i, p_list_i, c0b + 65536,  img,  u_it,  0, d0 + 256, text, 3, 2);
  jU.j[2] = mkjob(c0b + 131072, neg, 0, 0,           u_ntt, 0, d0 + 512, text, 3, 1);
  mgemm_k<0><<<dim3(8, 4, 3), 256, 0, stream>>>(jU, 512, 256);

  // 8. out = tanh(d0*(u@W) + bias) (NN, K=512) straight into d_out slots
  Jobs8 jO = {};
  jO.j[0] = mkjob(u_tt,  W_tt,  0, 0, out + 131072, b_tt,  d0,       0, 2, 1);
  jO.j[1] = mkjob(u_it,  W_it,  0, 0, out + 262144, b_it,  d0 + 256, 0, 2, 1);
  jO.j[2] = mkjob(u_ntt, W_ntt, 0, 0, out + 393216, b_ntt, d0 + 512, 0, 2, 1);
  mgemm_k<0><<<dim3(8, 4, 3), 256, 0, stream>>>(jO, 512, 512);

  // 9. main + img_feature passthrough
  combine_k<<<640, 256, 0, stream>>>(text, out + 131072, out + 262144, img_feature, out);
}